// Round 2
// 373.794 us; speedup vs baseline: 1.0465x; 1.0465x over previous
//
#include <hip/hip_runtime.h>
#include <cstddef>

// MemoryBank: H (B=32, D=128, T=4096) f32, units (D=128, S=512) f32
// out (B, S, T) f32 = softmax_s(2*H^t.units - ||units||^2), transposed store.
// h^2 term cancels in the softmax. Cross term via split-bf16 MFMA:
//   x = hi + lo (bf16 each);  h.u ~= hh*uh + hl*uh + hh*ul  (drop lo*lo, ~1e-5 rel)
//
// V2 (resubmit after infra failure): register-resident softmax.
//   - LDS 66KB -> 18KB, target 4 blocks/CU (was 2)
//   - H tile staged cooperatively (coalesced), split_bf16 done once (not 4x/wave)
//   - kk-outer GEMM keeps all 8 ntile accum pairs in regs (64 VGPR)
//   - row max/sum: in-lane over 8 s + 16-lane shfl_xor butterfly + 128-float LDS
//   - store: 4 rounds of 128-s LDS transpose (reuses A-staging region)
constexpr int kB  = 32;
constexpr int kD  = 128;
constexpr int kT  = 4096;
constexpr int kS  = 512;
constexpr int kMT = 32;    // t-rows per block

typedef __attribute__((ext_vector_type(8))) short bf16x8;   // 8 bf16 = 4 VGPRs
typedef __attribute__((ext_vector_type(4))) float f32x4;

__device__ __forceinline__ void split_bf16(float x, short& hi, short& lo) {
    union { float f; unsigned u; } a; a.f = x;
    unsigned r = (a.u + 0x7FFFu + ((a.u >> 16) & 1u)) & 0xFFFF0000u;  // RTN-even
    union { unsigned u; float f; } h; h.u = r;
    hi = (short)(r >> 16);
    float res = x - h.f;
    union { float f; unsigned u; } c; c.f = res;
    lo = (short)((c.u + 0x7FFFu + ((c.u >> 16) & 1u)) >> 16);
}

// ---------- prep: swizzle units into MFMA B-fragment order (hi/lo) + m2 ----------
// B-frag layout: idx = ((nt*4 + kk)*64 + lane)*8 + j
//   k = kk*32 + (lane>>4)*8 + j, n = nt*16 + (lane&15), value = units[k][n]
__global__ void prep_kernel(const float* __restrict__ units,
                            short* __restrict__ Bhi, short* __restrict__ Blo,
                            float* __restrict__ m2) {
    const int blk = blockIdx.x, tid = threadIdx.x;
    if (blk < 256) {
        int idx  = blk * 256 + tid;
        int j    = idx & 7;
        int lane = (idx >> 3) & 63;
        int kk   = (idx >> 9) & 3;
        int nt   = idx >> 11;
        int k = kk * 32 + (lane >> 4) * 8 + j;
        int n = nt * 16 + (lane & 15);
        float u = units[k * kS + n];
        short h, l; split_bf16(u, h, l);
        Bhi[idx] = h; Blo[idx] = l;
    } else {
        for (int s = tid; s < kS; s += 256) {
            float acc = 0.f;
#pragma unroll 8
            for (int d = 0; d < kD; ++d) {
                float u = units[d * kS + s];
                acc = fmaf(u, u, acc);
            }
            m2[s] = acc;
        }
    }
}

// ---------- main: block = 4 waves, 32 t-rows x 512 s, K=128 ----------
constexpr int kAStr = 136;   // shorts per m-row (128 + 8 pad) -> b128 reads hit bank floor
constexpr int kLStr = 132;   // floats per row in the 128-s store buffer (+4 pad)

__global__ __launch_bounds__(256, 4)
void mb_mfma(const float* __restrict__ H,
             const short* __restrict__ Bhi, const short* __restrict__ Blo,
             const float* __restrict__ m2, float* __restrict__ out) {
    // A-staging region (17408 B) later reused as the 32x132 f32 store buffer (16896 B)
    __shared__ __align__(16) union SMem {
        struct { short hi[kMT * kAStr]; short lo[kMT * kAStr]; } a;
        float ls[kMT * kLStr];
    } sm;
    __shared__ float redBuf[128];   // 4 waves x 32 rows partials
    __shared__ float rowM[kMT];
    __shared__ float rowInv[kMT];

    const int tid  = threadIdx.x;
    const int wave = tid >> 6;
    const int lane = tid & 63;
    const int q    = lane >> 4;
    const int nl   = lane & 15;
    const int t0   = blockIdx.x * kMT;
    const int b    = blockIdx.y;
    const float* Hb = H + ((size_t)b * kD) * kT + t0;

    // ---- stage A: cooperative coalesced load of H[128d x 32t], one split pass ----
    // thread (ms = t-local, kb): gathers 8 consecutive d for its t, packs b128.
    {
        const int ms = tid & 31;
        const int kb = tid >> 5;            // 0..7
#pragma unroll
        for (int half = 0; half < 2; ++half) {
            const int k0 = (kb + half * 8) * 8;     // 0..120 step 8
            bf16x8 vh, vl;
#pragma unroll
            for (int j = 0; j < 8; ++j) {
                float x = Hb[(size_t)(k0 + j) * kT + ms];
                short h, l; split_bf16(x, h, l);
                vh[j] = h; vl[j] = l;
            }
            *(bf16x8*)(sm.a.hi + ms * kAStr + k0) = vh;
            *(bf16x8*)(sm.a.lo + ms * kAStr + k0) = vl;
        }
    }
    __syncthreads();

    // ---- GEMM: kk-outer, wave owns ntiles nt = n8*4 + wave (interleaved) ----
    f32x4 acc[8][2];
#pragma unroll
    for (int n8 = 0; n8 < 8; ++n8)
#pragma unroll
        for (int mt = 0; mt < 2; ++mt)
            acc[n8][mt] = (f32x4){0.f, 0.f, 0.f, 0.f};

#pragma unroll
    for (int kk = 0; kk < 4; ++kk) {
        bf16x8 Ah[2], Al[2];
#pragma unroll
        for (int mt = 0; mt < 2; ++mt) {
            const int off = (mt * 16 + nl) * kAStr + kk * 32 + q * 8;
            Ah[mt] = *(const bf16x8*)(sm.a.hi + off);
            Al[mt] = *(const bf16x8*)(sm.a.lo + off);
        }
#pragma unroll
        for (int n8 = 0; n8 < 8; ++n8) {
            const int nt = n8 * 4 + wave;
            const int base = ((nt * 4 + kk) * 64 + lane) * 8;
            bf16x8 Bh = *(const bf16x8*)(Bhi + base);
            bf16x8 Bl = *(const bf16x8*)(Blo + base);
            acc[n8][0] = __builtin_amdgcn_mfma_f32_16x16x32_bf16(Ah[0], Bh, acc[n8][0], 0, 0, 0);
            acc[n8][1] = __builtin_amdgcn_mfma_f32_16x16x32_bf16(Ah[1], Bh, acc[n8][1], 0, 0, 0);
            acc[n8][0] = __builtin_amdgcn_mfma_f32_16x16x32_bf16(Al[0], Bh, acc[n8][0], 0, 0, 0);
            acc[n8][1] = __builtin_amdgcn_mfma_f32_16x16x32_bf16(Al[1], Bh, acc[n8][1], 0, 0, 0);
            acc[n8][0] = __builtin_amdgcn_mfma_f32_16x16x32_bf16(Ah[0], Bl, acc[n8][0], 0, 0, 0);
            acc[n8][1] = __builtin_amdgcn_mfma_f32_16x16x32_bf16(Ah[1], Bl, acc[n8][1], 0, 0, 0);
        }
    }

    // ---- logits in registers: l = 2*c - m2[s] ----
    // D layout: value acc[n8][mt][r] = C[row = mt*16+q*4+r][col = (n8*4+wave)*16+nl]
    float m2v[8];
#pragma unroll
    for (int n8 = 0; n8 < 8; ++n8) m2v[n8] = m2[(n8 * 4 + wave) * 16 + nl];
#pragma unroll
    for (int n8 = 0; n8 < 8; ++n8)
#pragma unroll
        for (int mt = 0; mt < 2; ++mt)
#pragma unroll
            for (int r = 0; r < 4; ++r)
                acc[n8][mt][r] = fmaf(2.f, acc[n8][mt][r], -m2v[n8]);

    // ---- row max: 8-in-lane + 16-lane butterfly + cross-wave via LDS ----
#pragma unroll
    for (int mt = 0; mt < 2; ++mt)
#pragma unroll
        for (int r = 0; r < 4; ++r) {
            float v = acc[0][mt][r];
#pragma unroll
            for (int n8 = 1; n8 < 8; ++n8) v = fmaxf(v, acc[n8][mt][r]);
            v = fmaxf(v, __shfl_xor(v, 1, 16));
            v = fmaxf(v, __shfl_xor(v, 2, 16));
            v = fmaxf(v, __shfl_xor(v, 4, 16));
            v = fmaxf(v, __shfl_xor(v, 8, 16));
            if (nl == 0) redBuf[wave * 32 + mt * 16 + q * 4 + r] = v;
        }
    __syncthreads();
    if (tid < kMT) {
        float v = redBuf[tid];
#pragma unroll
        for (int w = 1; w < 4; ++w) v = fmaxf(v, redBuf[w * 32 + tid]);
        rowM[tid] = v;
    }
    __syncthreads();

    // ---- exp + row sum (same reduction path; redBuf safely reused) ----
#pragma unroll
    for (int mt = 0; mt < 2; ++mt)
#pragma unroll
        for (int r = 0; r < 4; ++r) {
            const float M = rowM[mt * 16 + q * 4 + r];
            float s = 0.f;
#pragma unroll
            for (int n8 = 0; n8 < 8; ++n8) {
                float e = __expf(acc[n8][mt][r] - M);
                acc[n8][mt][r] = e;
                s += e;
            }
            s += __shfl_xor(s, 1, 16);
            s += __shfl_xor(s, 2, 16);
            s += __shfl_xor(s, 4, 16);
            s += __shfl_xor(s, 8, 16);
            if (nl == 0) redBuf[wave * 32 + mt * 16 + q * 4 + r] = s;
        }
    __syncthreads();
    if (tid < kMT) {
        float s = redBuf[tid] + redBuf[32 + tid] + redBuf[64 + tid] + redBuf[96 + tid];
        rowInv[tid] = 1.f / s;
    }
    __syncthreads();

    // ---- normalize in registers ----
#pragma unroll
    for (int mt = 0; mt < 2; ++mt)
#pragma unroll
        for (int r = 0; r < 4; ++r) {
            const float inv = rowInv[mt * 16 + q * 4 + r];
#pragma unroll
            for (int n8 = 0; n8 < 8; ++n8) acc[n8][mt][r] *= inv;
        }

    // ---- store: 4 rounds of 128 s through LDS transpose, f32x4 over t ----
    // round rnd covers n8 = {2rnd, 2rnd+1} for every wave -> s in [rnd*128, rnd*128+128)
    float* outB = out + ((size_t)b * kS) * kT + t0;
    const int i4 = (tid & 7) * 4;
    const int su = tid >> 3;
#pragma unroll
    for (int rnd = 0; rnd < 4; ++rnd) {
        __syncthreads();   // prev round's reads (or A reads, via softmax bars) done
#pragma unroll
        for (int h = 0; h < 2; ++h) {
            const int n8 = rnd * 2 + h;
            const int sl = h * 64 + wave * 16 + nl;
#pragma unroll
            for (int mt = 0; mt < 2; ++mt)
#pragma unroll
                for (int r = 0; r < 4; ++r)
                    sm.ls[(mt * 16 + q * 4 + r) * kLStr + sl] = acc[n8][mt][r];
        }
        __syncthreads();
#pragma unroll
        for (int p = 0; p < 4; ++p) {
            const int sl = su + p * 32;
            f32x4 v;
            v[0] = sm.ls[(i4 + 0) * kLStr + sl];
            v[1] = sm.ls[(i4 + 1) * kLStr + sl];
            v[2] = sm.ls[(i4 + 2) * kLStr + sl];
            v[3] = sm.ls[(i4 + 3) * kLStr + sl];
            __builtin_nontemporal_store(v, (f32x4*)(outB + (size_t)(rnd * 128 + sl) * kT + i4));
        }
    }
}

extern "C" void kernel_launch(void* const* d_in, const int* in_sizes, int n_in,
                              void* d_out, int out_size, void* d_ws, size_t ws_size,
                              hipStream_t stream) {
    const float* H     = (const float*)d_in[0];
    const float* units = (const float*)d_in[1];
    float* out = (float*)d_out;

    char* ws = (char*)d_ws;
    short* Bhi = (short*)ws;                      // 32*4*64*8 = 65536 shorts (128 KB)
    short* Blo = (short*)(ws + 131072);           // 128 KB
    float* m2  = (float*)(ws + 262144);           // 2 KB

    prep_kernel<<<dim3(257), dim3(256), 0, stream>>>(units, Bhi, Blo, m2);
    dim3 grid(kT / kMT, kB);                      // 128 x 32 = 4096 blocks
    mb_mfma<<<grid, dim3(256), 0, stream>>>(H, Bhi, Blo, m2, out);
}